// Round 2
// 392.343 us; speedup vs baseline: 1.1122x; 1.1122x over previous
//
#include <hip/hip_runtime.h>
#include <hip/hip_bf16.h>
#include <math.h>

// Problem constants
#define N1R 65536   // B*N1 query rows
#define N2R 16384   // B*N2 point rows
#define NPB 4096    // N2 per batch
#define NQB 16384   // N1 per batch
#define CC  256     // COUT
#define ASTRIDE 40  // LDS A-tile row stride in bf16 elems (80B: 16B-aligned, ~2-way banks)
#define NCELL 512   // 8x8x8 grid cells per batch
#define GRID_FAIL_R2 0.015625f   // (1/8)^2 coverage bound of the 27-cell block

typedef __attribute__((ext_vector_type(4))) float v4f;
typedef __attribute__((ext_vector_type(8))) short v8s;

static __device__ __forceinline__ short f2bs(float f) {
    union { __hip_bfloat16 h; short s; } u;
    u.h = __float2bfloat16(f);
    return u.s;
}

static __device__ __forceinline__ int cell_of(float x, float y, float z) {
    const int cx = min(7, (int)(x * 8.0f));
    const int cy = min(7, (int)(y * 8.0f));
    const int cz = min(7, (int)(z * 8.0f));
    return (cz << 6) | (cy << 3) | cx;
}

// branchless lexicographic (d, idx) top-3 insert; keeps b0<=b1<=b2 sorted
static __device__ __forceinline__ void ins3(float d, int si,
    float& b0, float& b1, float& b2, int& i0, int& i1, int& i2)
{
    const bool lt0 = (d < b0) | ((d == b0) & (si < i0));
    const bool lt1 = (d < b1) | ((d == b1) & (si < i1));
    const bool lt2 = (d < b2) | ((d == b2) & (si < i2));
    b2 = lt1 ? b1 : (lt2 ? d : b2);   i2 = lt1 ? i1 : (lt2 ? si : i2);
    b1 = lt0 ? b0 : (lt1 ? d : b1);   i1 = lt0 ? i0 : (lt1 ? si : i1);
    b0 = lt0 ? d  : b0;               i0 = lt0 ? si : i0;
}

// ---------------------------------------------------------------------------
// W transpose + bf16 convert: WT[n][k] = bf16(W[k][n]).  W: Kd x 256.
// ---------------------------------------------------------------------------
__global__ __launch_bounds__(256)
void wtrans_kernel(const float* __restrict__ W, short* __restrict__ WT, int Kd)
{
    const int i = blockIdx.x * 256 + threadIdx.x;   // over Kd*256
    const int k = i >> 8;
    const int n = i & 255;
    WT[(size_t)n * Kd + k] = f2bs(W[i]);
}

// ---------------------------------------------------------------------------
// Point augmentation + cell histogram: paug[i] = {x, y, z, (x*x+y*y)+z*z}
// (exact fp32, no FMA — bit-matches the reference's pp computation).
// ---------------------------------------------------------------------------
__global__ __launch_bounds__(256)
void paug_count_kernel(const float* __restrict__ p2, float4* __restrict__ paug,
                       int* __restrict__ counts_p)
{
#pragma clang fp contract(off)
    const int i = blockIdx.x * 256 + threadIdx.x;   // over N2R
    const float x = p2[(size_t)i * 3 + 0];
    const float y = p2[(size_t)i * 3 + 1];
    const float z = p2[(size_t)i * 3 + 2];
    float4 v;
    v.x = x; v.y = y; v.z = z;
    v.w = (x * x + y * y) + z * z;
    paug[i] = v;
    const int b = i >> 12;                // 4096 points per batch
    atomicAdd(&counts_p[b * NCELL + cell_of(x, y, z)], 1);
}

// ---------------------------------------------------------------------------
// Query cell histogram.
// ---------------------------------------------------------------------------
__global__ __launch_bounds__(256)
void qcount_kernel(const float* __restrict__ p1, int* __restrict__ counts_q)
{
    const int i = blockIdx.x * 256 + threadIdx.x;   // over N1R
    const float x = p1[(size_t)i * 3 + 0];
    const float y = p1[(size_t)i * 3 + 1];
    const float z = p1[(size_t)i * 3 + 2];
    const int b = i >> 14;                // 16384 queries per batch
    atomicAdd(&counts_q[b * NCELL + cell_of(x, y, z)], 1);
}

// ---------------------------------------------------------------------------
// Exclusive prefix over 512 cells, 4 batches x {points, queries}.
// Writes starts_p (with 513th sentinel) and initializes scatter cursors.
// ---------------------------------------------------------------------------
__global__ __launch_bounds__(512)
void prefix_kernel(const int* __restrict__ counts_p, int* __restrict__ cursors_p,
                   int* __restrict__ starts_p,
                   const int* __restrict__ counts_q, int* __restrict__ cursors_q)
{
    __shared__ int sc[512];
    const int t = threadIdx.x;
    for (int a = 0; a < 8; ++a) {
        const int b = a & 3;
        const int* cnt = (a < 4) ? counts_p + b * NCELL : counts_q + b * NCELL;
        const int v = cnt[t];
        sc[t] = v;
        __syncthreads();
        for (int off = 1; off < 512; off <<= 1) {
            const int add = (t >= off) ? sc[t - off] : 0;
            __syncthreads();
            sc[t] += add;
            __syncthreads();
        }
        const int incl = sc[t];
        const int excl = incl - v;
        if (a < 4) {
            starts_p[b * 513 + t] = excl;
            if (t == 511) starts_p[b * 513 + 512] = incl;   // == 4096
            cursors_p[b * NCELL + t] = excl;
        } else {
            cursors_q[b * NCELL + t] = excl;
        }
        __syncthreads();
    }
}

// ---------------------------------------------------------------------------
// Scatter points into cell-sorted order (batch-relative), keep original idx.
// ---------------------------------------------------------------------------
__global__ __launch_bounds__(256)
void scatter_p_kernel(const float4* __restrict__ paug, int* __restrict__ cursors,
                      float4* __restrict__ sortedP, unsigned short* __restrict__ sIdx)
{
    const int i = blockIdx.x * 256 + threadIdx.x;   // over N2R
    const float4 v = paug[i];
    const int b = i >> 12;
    const int cell = cell_of(v.x, v.y, v.z);
    const int pos = atomicAdd(&cursors[b * NCELL + cell], 1);
    sortedP[(size_t)b * NPB + pos] = v;
    sIdx[(size_t)b * NPB + pos] = (unsigned short)(i & 4095);
}

// ---------------------------------------------------------------------------
// Scatter queries into cell-sorted order (batch-local u16 ids).
// ---------------------------------------------------------------------------
__global__ __launch_bounds__(256)
void scatter_q_kernel(const float* __restrict__ p1, int* __restrict__ cursors,
                      unsigned short* __restrict__ qlist)
{
    const int i = blockIdx.x * 256 + threadIdx.x;   // over N1R
    const float x = p1[(size_t)i * 3 + 0];
    const float y = p1[(size_t)i * 3 + 1];
    const float z = p1[(size_t)i * 3 + 2];
    const int b = i >> 14;
    const int cell = cell_of(x, y, z);
    const int pos = atomicAdd(&cursors[b * NCELL + cell], 1);
    qlist[(size_t)b * NQB + pos] = (unsigned short)(i & 16383);
}

// ---------------------------------------------------------------------------
// Tiled GEMM: Y = X(rows x Kdim, fp32) @ W(Kdim x 256) + bias, fp32 out.
// 256 thr / 4 waves per 128x128 tile; wave -> 64x64 quadrant (4x4 MFMA grid).
// ---------------------------------------------------------------------------
__global__ __launch_bounds__(256)
void gemm_tile_kernel(const float* __restrict__ X,
                      const short* __restrict__ WT,
                      const float* __restrict__ bias,
                      float* __restrict__ Y,
                      int Kdim)
{
    __shared__ short As[128 * ASTRIDE];

    const int bm0 = blockIdx.x * 128;
    const int bn0 = blockIdx.y * 128;
    const int wave = threadIdx.x >> 6;
    const int lane = threadIdx.x & 63;
    const int wm0 = (wave >> 1) * 64;
    const int wn0 = (wave & 1) * 64;
    const int col = lane & 15, quad = lane >> 4;

    const int srow = threadIdx.x >> 1;
    const int skh  = (threadIdx.x & 1) * 16;
    const float* sbase = X + (size_t)(bm0 + srow) * Kdim + skh;
    short* sdst = As + srow * ASTRIDE + skh;

    v4f acc[4][4];
#pragma unroll
    for (int i = 0; i < 4; ++i)
#pragma unroll
        for (int j = 0; j < 4; ++j) acc[i][j] = (v4f){0.f, 0.f, 0.f, 0.f};

    const short* wbase = WT + (size_t)(bn0 + wn0 + col) * Kdim + quad * 8;

    // prologue A prefetch
    v4f f0 = *(const v4f*)(sbase);
    v4f f1 = *(const v4f*)(sbase + 4);
    v4f f2v = *(const v4f*)(sbase + 8);
    v4f f3 = *(const v4f*)(sbase + 12);

    for (int k0 = 0; k0 < Kdim; k0 += 32) {
        v8s lo, hi;
#pragma unroll
        for (int j = 0; j < 4; ++j) {
            lo[j] = f2bs(f0[j]); lo[j + 4] = f2bs(f1[j]);
            hi[j] = f2bs(f2v[j]); hi[j + 4] = f2bs(f3[j]);
        }
        __syncthreads();   // previous iteration's LDS reads complete
        *(v8s*)sdst = lo;
        *(v8s*)(sdst + 8) = hi;
        __syncthreads();

        // B fragments for this k (issued first -> earlier vmcnt slot)
        v8s bf[4];
#pragma unroll
        for (int ni = 0; ni < 4; ++ni)
            bf[ni] = *(const v8s*)(wbase + (size_t)(ni * 16) * Kdim + k0);

        // A-chunk prefetch for next iteration (stays in flight through MFMA)
        if (k0 + 32 < Kdim) {
            const float* np = sbase + k0 + 32;
            f0 = *(const v4f*)np;
            f1 = *(const v4f*)(np + 4);
            f2v = *(const v4f*)(np + 8);
            f3 = *(const v4f*)(np + 12);
        }

        v8s a[4];
#pragma unroll
        for (int mi = 0; mi < 4; ++mi)
            a[mi] = *(const v8s*)(As + (wm0 + mi * 16 + col) * ASTRIDE + quad * 8);
#pragma unroll
        for (int mi = 0; mi < 4; ++mi)
#pragma unroll
            for (int ni = 0; ni < 4; ++ni)
                acc[mi][ni] = __builtin_amdgcn_mfma_f32_16x16x32_bf16(a[mi], bf[ni], acc[mi][ni], 0, 0, 0);
    }

    // epilogue: bias + store fp32
#pragma unroll
    for (int ni = 0; ni < 4; ++ni) {
        const int n = bn0 + wn0 + ni * 16 + col;
        const float bv = bias[n];
#pragma unroll
        for (int mi = 0; mi < 4; ++mi) {
            const int m = bm0 + wm0 + mi * 16 + quad * 4;
#pragma unroll
            for (int r = 0; r < 4; ++r)
                Y[(size_t)(m + r) * CC + n] = acc[mi][ni][r] + bv;
        }
    }
}

// ---------------------------------------------------------------------------
// Column stats over 256 rows per block, float4-vectorized + LDS reduce.
// ---------------------------------------------------------------------------
__global__ __launch_bounds__(256)
void stat_accum_kernel(const float* __restrict__ Y,
                       float* __restrict__ sum, float* __restrict__ sumsq)
{
    __shared__ v4f rs[256], rq[256];
    const int cg = threadIdx.x & 63;     // column group (4 cols)
    const int rw = threadIdx.x >> 6;     // row phase 0..3
    const int r0 = blockIdx.x * 256;

    v4f s = {0.f, 0.f, 0.f, 0.f}, q = {0.f, 0.f, 0.f, 0.f};
    for (int r = r0 + rw; r < r0 + 256; r += 4) {
        v4f v = *(const v4f*)(Y + (size_t)r * CC + cg * 4);
        s += v;
        q += v * v;
    }
    rs[threadIdx.x] = s;
    rq[threadIdx.x] = q;
    __syncthreads();
    if (threadIdx.x < 64) {
        const int c = threadIdx.x;
        v4f ts = rs[c] + rs[64 + c] + rs[128 + c] + rs[192 + c];
        v4f tq = rq[c] + rq[64 + c] + rq[128 + c] + rq[192 + c];
#pragma unroll
        for (int j = 0; j < 4; ++j) {
            atomicAdd(&sum[c * 4 + j], ts[j]);
            atomicAdd(&sumsq[c * 4 + j], tq[j]);
        }
    }
}

// ---------------------------------------------------------------------------
// Finalize BN constants: a = g*rsqrt(var+eps), c = beta - a*mu
// ---------------------------------------------------------------------------
__global__ __launch_bounds__(512)
void finalize_kernel(const float* __restrict__ sums,
                     const float* __restrict__ g1, const float* __restrict__ be1,
                     const float* __restrict__ g2, const float* __restrict__ be2,
                     float* __restrict__ ac)
{
    const int t = threadIdx.x;           // 0..511
    const int c = t & 255;
    const int which = t >> 8;            // 0: BN1, 1: BN2
    const float* s = sums + which * 512;
    const double n = which ? (double)N2R : (double)N1R;
    const double mu = (double)s[c] / n;
    const double var = (double)s[c + 256] / n - mu * mu;
    const float g  = which ? g2[c]  : g1[c];
    const float be = which ? be2[c] : be1[c];
    const double a  = (double)g / sqrt(var + 1e-5);
    const double cv = (double)be - a * mu;
    ac[which * 512 + c]       = (float)a;
    ac[which * 512 + 256 + c] = (float)cv;
}

// ---------------------------------------------------------------------------
// In-place BN + ReLU for f2 (Y2 buffer), float4.
// ---------------------------------------------------------------------------
__global__ __launch_bounds__(256)
void bnrelu_kernel(float* __restrict__ Y, const float* __restrict__ ac)
{
    const int i = blockIdx.x * 256 + threadIdx.x;   // over N2R*CC/4
    const int c0 = (i & 63) * 4;
    v4f a4 = *(const v4f*)(ac + c0);
    v4f c4 = *(const v4f*)(ac + 256 + c0);
    v4f v = *(v4f*)(Y + (size_t)i * 4);
#pragma unroll
    for (int j = 0; j < 4; ++j)
        v[j] = fmaxf(fmaf(a4[j], v[j], c4[j]), 0.f);
    *(v4f*)(Y + (size_t)i * 4) = v;
}

// ---------------------------------------------------------------------------
// Grid KNN: cell-sorted queries scan their 27-cell neighborhood against the
// batch's cell-sorted points staged in LDS.  Exact fp32 distances (same
// formula as the brute-force version, bit-matching the reference);
// lexicographic (d, idx) top-3.  Coverage proof: every point within 0.125 of
// q lies inside the clamped 27-cell block (cell width 1/8, per-axis delta
// <=1), so b2 < 0.125^2 certifies exactness; otherwise the query goes to
// failList for brute-force fallback.
// Block: 256 thr = 128 queries x 2 half-scans (cells 0..13 / 14..26).
// LDS ~79 KB (gfx950 supports up to 160 KB/WG) -> 2 blocks/CU.
// ---------------------------------------------------------------------------
__global__ __launch_bounds__(256)
void knn_grid_kernel(const float* __restrict__ p1,
                     const float4* __restrict__ sortedP,
                     const unsigned short* __restrict__ sIdx16,
                     const int* __restrict__ starts_p,
                     const unsigned short* __restrict__ qlist,
                     int* __restrict__ idx_out, float* __restrict__ w_out,
                     int* __restrict__ failCount, int* __restrict__ failList)
{
#pragma clang fp contract(off)
    __shared__ float4 sP[NPB];                 // 64 KB
    __shared__ unsigned short sI[NPB];         // 8 KB
    __shared__ int sS[513];                    // 2 KB
    __shared__ float mD[128 * 3];              // 1.5 KB
    __shared__ int   mI[128 * 3];              // 1.5 KB

    const int b = blockIdx.x >> 7;             // 128 blocks per batch
    const int slot0 = (blockIdx.x & 127) * 128;
    const int tid = threadIdx.x;
    const int lq = tid & 127;                  // query slot within block
    const int half = tid >> 7;

    // stage the batch's cell-sorted points + idx + starts
    {
        const float4* gp = sortedP + (size_t)b * NPB;
        for (int i = tid; i < NPB; i += 256) sP[i] = gp[i];
        const unsigned int* gi = (const unsigned int*)(sIdx16 + (size_t)b * NPB);
        unsigned int* li = (unsigned int*)sI;
        for (int i = tid; i < NPB / 2; i += 256) li[i] = gi[i];
        const int* gs = starts_p + b * 513;
        for (int i = tid; i < 513; i += 256) sS[i] = gs[i];
    }

    const int q = qlist[(size_t)b * NQB + slot0 + lq];   // batch-local query id
    const int qid = b * NQB + q;
    const float qx = p1[(size_t)qid * 3 + 0];
    const float qy = p1[(size_t)qid * 3 + 1];
    const float qz = p1[(size_t)qid * 3 + 2];
    const float qq = (qx * qx + qy * qy) + qz * qz;
    const int cqx = min(7, (int)(qx * 8.0f));
    const int cqy = min(7, (int)(qy * 8.0f));
    const int cqz = min(7, (int)(qz * 8.0f));

    __syncthreads();

    float b0 = 3.0e38f, b1 = 3.0e38f, b2 = 3.0e38f;
    int i0 = 0x7fffffff, i1 = 0x7fffffff, i2 = 0x7fffffff;

    int n = 0;
    for (int dz = -1; dz <= 1; ++dz)
        for (int dy = -1; dy <= 1; ++dy)
            for (int dx = -1; dx <= 1; ++dx, ++n) {
                if (half ? (n < 14) : (n >= 14)) continue;   // 14 / 13 cell split
                const int cz = cqz + dz, cy = cqy + dy, cx = cqx + dx;
                if (((unsigned)cz | (unsigned)cy | (unsigned)cx) > 7u) continue;
                const int cell = (cz << 6) | (cy << 3) | cx;
                const int ks = sS[cell], ke = sS[cell + 1];
                for (int k = ks; k < ke; ++k) {
                    const float4 P = sP[k];
                    const int si = sI[k];
                    const float dot = fmaf(qz, P.z, fmaf(qy, P.y, qx * P.x));
                    const float d = fmaf(-2.0f, dot, qq + P.w);
                    ins3(d, si, b0, b1, b2, i0, i1, i2);
                }
            }

    if (half) {
        mD[lq * 3 + 0] = b0; mD[lq * 3 + 1] = b1; mD[lq * 3 + 2] = b2;
        mI[lq * 3 + 0] = i0; mI[lq * 3 + 1] = i1; mI[lq * 3 + 2] = i2;
    }
    __syncthreads();
    if (!half) {
#pragma unroll
        for (int r = 0; r < 3; ++r)
            ins3(mD[lq * 3 + r], mI[lq * 3 + r], b0, b1, b2, i0, i1, i2);

        if (!(b2 < GRID_FAIL_R2)) {            // includes <3-found case (b2=3e38)
            const int p = atomicAdd(failCount, 1);
            if (p < N1R) failList[p] = qid;    // capacity-exact; guard is free
        }
        const float r0 = 1.0f / (fmaxf(b0, 0.0f) + 1e-8f);
        const float r1 = 1.0f / (fmaxf(b1, 0.0f) + 1e-8f);
        const float r2 = 1.0f / (fmaxf(b2, 0.0f) + 1e-8f);
        const float rs = (r0 + r1) + r2;
        idx_out[(size_t)qid * 3 + 0] = i0;
        idx_out[(size_t)qid * 3 + 1] = i1;
        idx_out[(size_t)qid * 3 + 2] = i2;
        w_out[(size_t)qid * 3 + 0] = r0 / rs;
        w_out[(size_t)qid * 3 + 1] = r1 / rs;
        w_out[(size_t)qid * 3 + 2] = r2 / rs;
    }
}

// ---------------------------------------------------------------------------
// Brute-force fallback: one wave per failed query, lanes split 4096 points,
// butterfly shuffle-merge of per-lane top-3 triples.  Exact, tiny workload.
// ---------------------------------------------------------------------------
__global__ __launch_bounds__(256)
void knn_bf_kernel(const float* __restrict__ p1,
                   const float4* __restrict__ paug,
                   const int* __restrict__ failCount,
                   const int* __restrict__ failList,
                   int* __restrict__ idx_out, float* __restrict__ w_out)
{
#pragma clang fp contract(off)
    const int nf = min(*failCount, N1R);
    const int gw = (blockIdx.x * 256 + threadIdx.x) >> 6;
    const int lane = threadIdx.x & 63;
    const int nw = (gridDim.x * 256) >> 6;

    for (int fi = gw; fi < nf; fi += nw) {
        const int qid = failList[fi];
        const int b = qid >> 14;
        const float qx = p1[(size_t)qid * 3 + 0];
        const float qy = p1[(size_t)qid * 3 + 1];
        const float qz = p1[(size_t)qid * 3 + 2];
        const float qq = (qx * qx + qy * qy) + qz * qz;

        float b0 = 3.0e38f, b1 = 3.0e38f, b2 = 3.0e38f;
        int i0 = 0x7fffffff, i1 = 0x7fffffff, i2 = 0x7fffffff;

        const float4* pb = paug + (size_t)b * NPB;
        for (int j = lane; j < NPB; j += 64) {
            const float4 P = pb[j];
            const float dot = fmaf(qz, P.z, fmaf(qy, P.y, qx * P.x));
            const float d = fmaf(-2.0f, dot, qq + P.w);
            ins3(d, j, b0, b1, b2, i0, i1, i2);
        }
        // butterfly merge across the wave
        for (int m = 1; m < 64; m <<= 1) {
            const float c0 = __shfl_xor(b0, m), c1 = __shfl_xor(b1, m), c2 = __shfl_xor(b2, m);
            const int j0 = __shfl_xor(i0, m), j1 = __shfl_xor(i1, m), j2 = __shfl_xor(i2, m);
            ins3(c0, j0, b0, b1, b2, i0, i1, i2);
            ins3(c1, j1, b0, b1, b2, i0, i1, i2);
            ins3(c2, j2, b0, b1, b2, i0, i1, i2);
        }
        if (lane == 0) {
            const float r0 = 1.0f / (fmaxf(b0, 0.0f) + 1e-8f);
            const float r1 = 1.0f / (fmaxf(b1, 0.0f) + 1e-8f);
            const float r2 = 1.0f / (fmaxf(b2, 0.0f) + 1e-8f);
            const float rs = (r0 + r1) + r2;
            idx_out[(size_t)qid * 3 + 0] = i0;
            idx_out[(size_t)qid * 3 + 1] = i1;
            idx_out[(size_t)qid * 3 + 2] = i2;
            w_out[(size_t)qid * 3 + 0] = r0 / rs;
            w_out[(size_t)qid * 3 + 1] = r1 / rs;
            w_out[(size_t)qid * 3 + 2] = r2 / rs;
        }
    }
}

// ---------------------------------------------------------------------------
// Final: out[row][c] = relu(a1*Y1 + c1) + sum_k w_k * f2[idx_k][c], float4.
// ---------------------------------------------------------------------------
__global__ __launch_bounds__(256)
void final_kernel(float* __restrict__ Y1out,
                  const float* __restrict__ f2,
                  const float* __restrict__ ac,        // a1[256], c1[256]
                  const int* __restrict__ idx, const float* __restrict__ w)
{
    const int r = blockIdx.x * 4 + (threadIdx.x >> 6);
    const int cg = threadIdx.x & 63;
    const int b = r >> 14;

    v4f a4 = *(const v4f*)(ac + cg * 4);
    v4f c4 = *(const v4f*)(ac + 256 + cg * 4);
    v4f y = *(const v4f*)(Y1out + (size_t)r * CC + cg * 4);
    v4f s;
#pragma unroll
    for (int j = 0; j < 4; ++j)
        s[j] = fmaxf(fmaf(a4[j], y[j], c4[j]), 0.f);

    const int*   ir = idx + (size_t)r * 3;
    const float* wr = w   + (size_t)r * 3;
#pragma unroll
    for (int k = 0; k < 3; ++k) {
        const int id = ir[k];
        const float wk = wr[k];
        v4f g = *(const v4f*)(f2 + ((size_t)(b * NPB + id)) * CC + cg * 4);
#pragma unroll
        for (int j = 0; j < 4; ++j)
            s[j] = fmaf(wk, g[j], s[j]);
    }
    *(v4f*)(Y1out + (size_t)r * CC + cg * 4) = s;
}

// ---------------------------------------------------------------------------
extern "C" void kernel_launch(void* const* d_in, const int* in_sizes, int n_in,
                              void* d_out, int out_size, void* d_ws, size_t ws_size,
                              hipStream_t stream)
{
    const float* point1 = (const float*)d_in[0];
    const float* feat1  = (const float*)d_in[1];
    const float* point2 = (const float*)d_in[2];
    const float* feat2  = (const float*)d_in[3];
    const float* W1     = (const float*)d_in[4];
    const float* b1     = (const float*)d_in[5];
    const float* g1     = (const float*)d_in[6];
    const float* beta1  = (const float*)d_in[7];
    const float* W2     = (const float*)d_in[8];
    const float* b2     = (const float*)d_in[9];
    const float* g2     = (const float*)d_in[10];
    const float* beta2  = (const float*)d_in[11];

    float* Y1 = (float*)d_out;                            // 64 MB (reused as output)

    char* ws = (char*)d_ws;
    float*          Y2       = (float*)ws;                                   // 16 MB
    float*          stats    = (float*)(ws + (size_t)16777216);              // 4 KB
    int*            counts_p = (int*)  (ws + (size_t)16781312);              // 8 KB
    int*            counts_q = (int*)  (ws + (size_t)16789504);              // 8 KB
    int*            failCnt  = (int*)  (ws + (size_t)16797696);              // 4 KB pad
    int*            cursors_p= (int*)  (ws + (size_t)16801792);              // 8 KB
    int*            cursors_q= (int*)  (ws + (size_t)16809984);              // 8 KB
    int*            starts_p = (int*)  (ws + (size_t)16818176);              // 8.2 KB
    float*          ac       = (float*)(ws + (size_t)16826624);              // 4 KB
    unsigned short* sIdx16   = (unsigned short*)(ws + (size_t)16830720);     // 32 KB
    unsigned short* qlist    = (unsigned short*)(ws + (size_t)16863488);     // 128 KB
    int*            failList = (int*)  (ws + (size_t)16994560);              // 256 KB
    float4*         sortedP  = (float4*)(ws + (size_t)17256704);             // 256 KB
    int*            idxb     = (int*)  (ws + (size_t)17518848);              // 768 KB
    float*          wb       = (float*)(ws + (size_t)18305280);              // 768 KB
    short*          WT1      = (short*)(ws + (size_t)19091712);              // 128 KB
    short*          WT2      = (short*)(ws + (size_t)19222784);              // 256 KB
    float4*         paug     = (float4*)(ws + (size_t)19484928);             // 256 KB

    // zero: stats (4KB) + counts_p (8KB) + counts_q (8KB) + failCnt (4KB)
    hipMemsetAsync(stats, 0, 24576, stream);

    // Tiny prep kernels
    wtrans_kernel<<<256, 256, 0, stream>>>(W1, WT1, 256);
    wtrans_kernel<<<512, 256, 0, stream>>>(W2, WT2, 512);

    // Cell-grid build: histograms -> prefix/cursors -> scatters
    paug_count_kernel<<<N2R / 256, 256, 0, stream>>>(point2, paug, counts_p);
    qcount_kernel<<<N1R / 256, 256, 0, stream>>>(point1, counts_q);
    prefix_kernel<<<1, 512, 0, stream>>>(counts_p, cursors_p, starts_p, counts_q, cursors_q);
    scatter_p_kernel<<<N2R / 256, 256, 0, stream>>>(paug, cursors_p, sortedP, sIdx16);
    scatter_q_kernel<<<N1R / 256, 256, 0, stream>>>(point1, cursors_q, qlist);

    // Tiled GEMMs: grid = (rows/128, 256/128)
    gemm_tile_kernel<<<dim3(N1R / 128, 2), 256, 0, stream>>>(feat1, WT1, b1, Y1, 256);
    gemm_tile_kernel<<<dim3(N2R / 128, 2), 256, 0, stream>>>(feat2, WT2, b2, Y2, 512);

    // BN stats (256 rows per block)
    stat_accum_kernel<<<N1R / 256, 256, 0, stream>>>(Y1, stats + 0,   stats + 256);
    stat_accum_kernel<<<N2R / 256, 256, 0, stream>>>(Y2, stats + 512, stats + 768);
    finalize_kernel<<<1, 512, 0, stream>>>(stats, g1, beta1, g2, beta2, ac);

    // f2 = relu(bn(Y2)) in place (float4)
    bnrelu_kernel<<<(N2R * CC / 4) / 256, 256, 0, stream>>>(Y2, ac + 512);

    // Grid KNN (exact) + brute-force fallback for boundary failures
    knn_grid_kernel<<<512, 256, 0, stream>>>(point1, sortedP, sIdx16, starts_p,
                                             qlist, idxb, wb, failCnt, failList);
    knn_bf_kernel<<<256, 256, 0, stream>>>(point1, paug, failCnt, failList, idxb, wb);

    // out = relu(bn(Y1)) + weighted gather of f2   (in-place on d_out, float4)
    final_kernel<<<N1R / 4, 256, 0, stream>>>(Y1, Y2, ac, idxb, wb);
}

// Round 3
// 350.263 us; speedup vs baseline: 1.2459x; 1.1201x over previous
//
#include <hip/hip_runtime.h>
#include <hip/hip_bf16.h>
#include <math.h>

// Problem constants
#define N1R 65536   // B*N1 query rows
#define N2R 16384   // B*N2 point rows
#define NPB 4096    // N2 per batch
#define NQB 16384   // N1 per batch
#define CC  256     // COUT
#define KC  64      // GEMM K-chunk (floats) staged per LDS buffer
#define NCELL 512   // 8x8x8 grid cells per batch
#define GRID_FAIL_R2 0.015625f   // (1/8)^2 coverage bound of the 27-cell block

typedef __attribute__((ext_vector_type(4))) float v4f;
typedef __attribute__((ext_vector_type(8))) short v8s;

typedef const __attribute__((address_space(1))) float glb_f32;
typedef __attribute__((address_space(3))) float lds_f32;

static __device__ __forceinline__ void gload16(const float* g, float* l) {
    // async global->LDS, 16B per lane; LDS dest = base + lane*16 (linear)
    __builtin_amdgcn_global_load_lds((glb_f32*)g, (lds_f32*)l, 16, 0, 0);
}

static __device__ __forceinline__ short f2bs(float f) {
    union { __hip_bfloat16 h; short s; } u;
    u.h = __float2bfloat16(f);
    return u.s;
}

static __device__ __forceinline__ int cell_of(float x, float y, float z) {
    const int cx = min(7, (int)(x * 8.0f));
    const int cy = min(7, (int)(y * 8.0f));
    const int cz = min(7, (int)(z * 8.0f));
    return (cz << 6) | (cy << 3) | cx;
}

// branchless lexicographic (d, idx) top-3 insert; keeps b0<=b1<=b2 sorted
static __device__ __forceinline__ void ins3(float d, int si,
    float& b0, float& b1, float& b2, int& i0, int& i1, int& i2)
{
    const bool lt0 = (d < b0) | ((d == b0) & (si < i0));
    const bool lt1 = (d < b1) | ((d == b1) & (si < i1));
    const bool lt2 = (d < b2) | ((d == b2) & (si < i2));
    b2 = lt1 ? b1 : (lt2 ? d : b2);   i2 = lt1 ? i1 : (lt2 ? si : i2);
    b1 = lt0 ? b0 : (lt1 ? d : b1);   i1 = lt0 ? i0 : (lt1 ? si : i1);
    b0 = lt0 ? d  : b0;               i0 = lt0 ? si : i0;
}

// ---------------------------------------------------------------------------
// W transpose + bf16 convert: WT[n][k] = bf16(W[k][n]).  W: Kd x 256.
// ---------------------------------------------------------------------------
__global__ __launch_bounds__(256)
void wtrans_kernel(const float* __restrict__ W, short* __restrict__ WT, int Kd)
{
    const int i = blockIdx.x * 256 + threadIdx.x;   // over Kd*256
    const int k = i >> 8;
    const int n = i & 255;
    WT[(size_t)n * Kd + k] = f2bs(W[i]);
}

// ---------------------------------------------------------------------------
// Point augmentation + cell histogram: paug[i] = {x, y, z, (x*x+y*y)+z*z}
// (exact fp32, no FMA — bit-matches the reference's pp computation).
// ---------------------------------------------------------------------------
__global__ __launch_bounds__(256)
void paug_count_kernel(const float* __restrict__ p2, float4* __restrict__ paug,
                       int* __restrict__ counts_p)
{
#pragma clang fp contract(off)
    const int i = blockIdx.x * 256 + threadIdx.x;   // over N2R
    const float x = p2[(size_t)i * 3 + 0];
    const float y = p2[(size_t)i * 3 + 1];
    const float z = p2[(size_t)i * 3 + 2];
    float4 v;
    v.x = x; v.y = y; v.z = z;
    v.w = (x * x + y * y) + z * z;
    paug[i] = v;
    const int b = i >> 12;                // 4096 points per batch
    atomicAdd(&counts_p[b * NCELL + cell_of(x, y, z)], 1);
}

// ---------------------------------------------------------------------------
// Query cell histogram.
// ---------------------------------------------------------------------------
__global__ __launch_bounds__(256)
void qcount_kernel(const float* __restrict__ p1, int* __restrict__ counts_q)
{
    const int i = blockIdx.x * 256 + threadIdx.x;   // over N1R
    const float x = p1[(size_t)i * 3 + 0];
    const float y = p1[(size_t)i * 3 + 1];
    const float z = p1[(size_t)i * 3 + 2];
    const int b = i >> 14;                // 16384 queries per batch
    atomicAdd(&counts_q[b * NCELL + cell_of(x, y, z)], 1);
}

// ---------------------------------------------------------------------------
// Exclusive prefix over 512 cells, 4 batches x {points, queries}.
// Writes starts_p (with 513th sentinel) and initializes scatter cursors.
// ---------------------------------------------------------------------------
__global__ __launch_bounds__(512)
void prefix_kernel(const int* __restrict__ counts_p, int* __restrict__ cursors_p,
                   int* __restrict__ starts_p,
                   const int* __restrict__ counts_q, int* __restrict__ cursors_q)
{
    __shared__ int sc[512];
    const int t = threadIdx.x;
    for (int a = 0; a < 8; ++a) {
        const int b = a & 3;
        const int* cnt = (a < 4) ? counts_p + b * NCELL : counts_q + b * NCELL;
        const int v = cnt[t];
        sc[t] = v;
        __syncthreads();
        for (int off = 1; off < 512; off <<= 1) {
            const int add = (t >= off) ? sc[t - off] : 0;
            __syncthreads();
            sc[t] += add;
            __syncthreads();
        }
        const int incl = sc[t];
        const int excl = incl - v;
        if (a < 4) {
            starts_p[b * 513 + t] = excl;
            if (t == 511) starts_p[b * 513 + 512] = incl;   // == 4096
            cursors_p[b * NCELL + t] = excl;
        } else {
            cursors_q[b * NCELL + t] = excl;
        }
        __syncthreads();
    }
}

// ---------------------------------------------------------------------------
// Scatter points into cell-sorted order (batch-relative), keep original idx.
// ---------------------------------------------------------------------------
__global__ __launch_bounds__(256)
void scatter_p_kernel(const float4* __restrict__ paug, int* __restrict__ cursors,
                      float4* __restrict__ sortedP, unsigned short* __restrict__ sIdx)
{
    const int i = blockIdx.x * 256 + threadIdx.x;   // over N2R
    const float4 v = paug[i];
    const int b = i >> 12;
    const int cell = cell_of(v.x, v.y, v.z);
    const int pos = atomicAdd(&cursors[b * NCELL + cell], 1);
    sortedP[(size_t)b * NPB + pos] = v;
    sIdx[(size_t)b * NPB + pos] = (unsigned short)(i & 4095);
}

// ---------------------------------------------------------------------------
// Scatter queries into cell-sorted order (batch-local u16 ids).
// ---------------------------------------------------------------------------
__global__ __launch_bounds__(256)
void scatter_q_kernel(const float* __restrict__ p1, int* __restrict__ cursors,
                      unsigned short* __restrict__ qlist)
{
    const int i = blockIdx.x * 256 + threadIdx.x;   // over N1R
    const float x = p1[(size_t)i * 3 + 0];
    const float y = p1[(size_t)i * 3 + 1];
    const float z = p1[(size_t)i * 3 + 2];
    const int b = i >> 14;
    const int cell = cell_of(x, y, z);
    const int pos = atomicAdd(&cursors[b * NCELL + cell], 1);
    qlist[(size_t)b * NQB + pos] = (unsigned short)(i & 16383);
}

// ---------------------------------------------------------------------------
// Fused tiled GEMM + column-stats: Y = X(rows x Kdim, f32) @ WT^T + bias,
// and atomicAdd per-column sum / sumsq of Y (for BN) from the accumulators.
//
// 128x128 tile, 4 waves (2x2), each wave a 64x64 quadrant (4x4 MFMA grid).
// A staged f32 into LDS via global_load_lds (16B/lane; one wave-instr = 4
// rows x 64 floats), double-buffered KC=64 chunks (64 KB LDS).  Row stride
// 256B == 0 mod 128B would be a 16-way bank conflict on ds_read_b128, so the
// 16B slots are XOR-swizzled (slot ^= row&7) on BOTH sides: pre-swizzled
// per-lane GLOBAL source address + same XOR on the LDS read (linear dest).
// B-fragment global loads are issued BEFORE the next-chunk stage so their
// waitcnt is vmcnt(8), leaving the stage prefetch in flight through MFMA.
// ---------------------------------------------------------------------------
__global__ __launch_bounds__(256)
void gemm_fused_kernel(const float* __restrict__ X,
                       const short* __restrict__ WT,
                       const float* __restrict__ bias,
                       float* __restrict__ Y,
                       float* __restrict__ sum, float* __restrict__ sumsq,
                       int Kdim)
{
    __shared__ float As[2][128 * KC];          // 64 KB double buffer

    const int bm0 = blockIdx.x * 128;
    const int bn0 = blockIdx.y * 128;
    const int tid  = threadIdx.x;
    const int wave = tid >> 6;
    const int lane = tid & 63;
    const int wm0 = (wave >> 1) * 64;
    const int wn0 = (wave & 1) * 64;
    const int col = lane & 15, quad = lane >> 4;

    const int srow4 = lane >> 4;               // row within 4-row stage group
    const int sslot = lane & 15;               // physical 16B slot

    v4f acc[4][4];
#pragma unroll
    for (int i = 0; i < 4; ++i)
#pragma unroll
        for (int j = 0; j < 4; ++j) acc[i][j] = (v4f){0.f, 0.f, 0.f, 0.f};

    const short* wbase = WT + (size_t)(bn0 + wn0 + col) * Kdim + quad * 8;

    // prologue: stage chunk 0 into buffer 0
#pragma unroll
    for (int j = 0; j < 8; ++j) {
        const int r = (wave * 8 + j) * 4 + srow4;
        const float* g = X + (size_t)(bm0 + r) * Kdim + ((sslot ^ (r & 7)) << 2);
        gload16(g, &As[0][(wave * 8 + j) * 256]);
    }

    const int NC = Kdim / KC;
    for (int c = 0; c < NC; ++c) {
        const int k0 = c * KC;
        __syncthreads();                       // stage(c) drained; buf[(c+1)&1] readers done
        const float* bufc = As[c & 1];

        // B fragments for this chunk (before stage-issue -> waited at vmcnt(8))
        v8s bf[4][2];
#pragma unroll
        for (int ni = 0; ni < 4; ++ni)
#pragma unroll
            for (int ks = 0; ks < 2; ++ks)
                bf[ni][ks] = *(const v8s*)(wbase + (size_t)(ni * 16) * Kdim + k0 + ks * 32);

        // stage chunk c+1 (overlaps this chunk's compute)
        if (c + 1 < NC) {
            float* bufn = As[(c + 1) & 1];
#pragma unroll
            for (int j = 0; j < 8; ++j) {
                const int r = (wave * 8 + j) * 4 + srow4;
                const float* g = X + (size_t)(bm0 + r) * Kdim + (k0 + KC) + ((sslot ^ (r & 7)) << 2);
                gload16(g, &bufn[(wave * 8 + j) * 256]);
            }
        }

        // compute: 2 k-steps of 32
#pragma unroll
        for (int ks = 0; ks < 2; ++ks) {
            const int sbase = ks * 8 + quad * 2;           // logical slot of first 16B
            v8s a[4];
#pragma unroll
            for (int mi = 0; mi < 4; ++mi) {
                const int m = wm0 + mi * 16 + col;
                const float* rowp = bufc + m * KC;
                const v4f pa = *(const v4f*)(rowp + ((sbase ^ (m & 7)) << 2));
                const v4f pb = *(const v4f*)(rowp + (((sbase + 1) ^ (m & 7)) << 2));
                v8s t;
#pragma unroll
                for (int j = 0; j < 4; ++j) { t[j] = f2bs(pa[j]); t[j + 4] = f2bs(pb[j]); }
                a[mi] = t;
            }
#pragma unroll
            for (int mi = 0; mi < 4; ++mi)
#pragma unroll
                for (int ni = 0; ni < 4; ++ni)
                    acc[mi][ni] = __builtin_amdgcn_mfma_f32_16x16x32_bf16(a[mi], bf[ni][ks], acc[mi][ni], 0, 0, 0);
        }
    }

    // epilogue: bias + store + fused column stats (sum / sumsq over rows)
#pragma unroll
    for (int ni = 0; ni < 4; ++ni) {
        const int n = bn0 + wn0 + ni * 16 + col;
        const float bv = bias[n];
        float s = 0.f, q = 0.f;
#pragma unroll
        for (int mi = 0; mi < 4; ++mi) {
            const int m = bm0 + wm0 + mi * 16 + quad * 4;
#pragma unroll
            for (int r = 0; r < 4; ++r) {
                const float y = acc[mi][ni][r] + bv;
                Y[(size_t)(m + r) * CC + n] = y;
                s += y; q += y * y;
            }
        }
        s += __shfl_xor(s, 16); q += __shfl_xor(q, 16);
        s += __shfl_xor(s, 32); q += __shfl_xor(q, 32);
        if (quad == 0) { atomicAdd(&sum[n], s); atomicAdd(&sumsq[n], q); }
    }
}

// ---------------------------------------------------------------------------
// Finalize BN constants: a = g*rsqrt(var+eps), c = beta - a*mu
// ---------------------------------------------------------------------------
__global__ __launch_bounds__(512)
void finalize_kernel(const float* __restrict__ sums,
                     const float* __restrict__ g1, const float* __restrict__ be1,
                     const float* __restrict__ g2, const float* __restrict__ be2,
                     float* __restrict__ ac)
{
    const int t = threadIdx.x;           // 0..511
    const int c = t & 255;
    const int which = t >> 8;            // 0: BN1, 1: BN2
    const float* s = sums + which * 512;
    const double n = which ? (double)N2R : (double)N1R;
    const double mu = (double)s[c] / n;
    const double var = (double)s[c + 256] / n - mu * mu;
    const float g  = which ? g2[c]  : g1[c];
    const float be = which ? be2[c] : be1[c];
    const double a  = (double)g / sqrt(var + 1e-5);
    const double cv = (double)be - a * mu;
    ac[which * 512 + c]       = (float)a;
    ac[which * 512 + 256 + c] = (float)cv;
}

// ---------------------------------------------------------------------------
// Grid KNN: cell-sorted queries scan their 27-cell neighborhood against the
// batch's cell-sorted points staged in LDS.  Exact fp32 distances
// (bit-matching the reference); lexicographic (d, idx) top-3.  Coverage:
// every point within 0.125 of q lies inside the clamped 27-cell block, so
// b2 < 0.125^2 certifies exactness; else brute-force fallback.
// Block: 256 thr = 128 queries x 2 half-scans (cells 0..13 / 14..26).
// ---------------------------------------------------------------------------
__global__ __launch_bounds__(256)
void knn_grid_kernel(const float* __restrict__ p1,
                     const float4* __restrict__ sortedP,
                     const unsigned short* __restrict__ sIdx16,
                     const int* __restrict__ starts_p,
                     const unsigned short* __restrict__ qlist,
                     int* __restrict__ idx_out, float* __restrict__ w_out,
                     int* __restrict__ failCount, int* __restrict__ failList)
{
#pragma clang fp contract(off)
    __shared__ float4 sP[NPB];                 // 64 KB
    __shared__ unsigned short sI[NPB];         // 8 KB
    __shared__ int sS[513];                    // 2 KB
    __shared__ float mD[128 * 3];              // 1.5 KB
    __shared__ int   mI[128 * 3];              // 1.5 KB

    const int b = blockIdx.x >> 7;             // 128 blocks per batch
    const int slot0 = (blockIdx.x & 127) * 128;
    const int tid = threadIdx.x;
    const int lq = tid & 127;                  // query slot within block
    const int half = tid >> 7;

    // stage the batch's cell-sorted points + idx + starts
    {
        const float4* gp = sortedP + (size_t)b * NPB;
        for (int i = tid; i < NPB; i += 256) sP[i] = gp[i];
        const unsigned int* gi = (const unsigned int*)(sIdx16 + (size_t)b * NPB);
        unsigned int* li = (unsigned int*)sI;
        for (int i = tid; i < NPB / 2; i += 256) li[i] = gi[i];
        const int* gs = starts_p + b * 513;
        for (int i = tid; i < 513; i += 256) sS[i] = gs[i];
    }

    const int q = qlist[(size_t)b * NQB + slot0 + lq];   // batch-local query id
    const int qid = b * NQB + q;
    const float qx = p1[(size_t)qid * 3 + 0];
    const float qy = p1[(size_t)qid * 3 + 1];
    const float qz = p1[(size_t)qid * 3 + 2];
    const float qq = (qx * qx + qy * qy) + qz * qz;
    const int cqx = min(7, (int)(qx * 8.0f));
    const int cqy = min(7, (int)(qy * 8.0f));
    const int cqz = min(7, (int)(qz * 8.0f));

    __syncthreads();

    float b0 = 3.0e38f, b1 = 3.0e38f, b2 = 3.0e38f;
    int i0 = 0x7fffffff, i1 = 0x7fffffff, i2 = 0x7fffffff;

    int n = 0;
    for (int dz = -1; dz <= 1; ++dz)
        for (int dy = -1; dy <= 1; ++dy)
            for (int dx = -1; dx <= 1; ++dx, ++n) {
                if (half ? (n < 14) : (n >= 14)) continue;   // 14 / 13 cell split
                const int cz = cqz + dz, cy = cqy + dy, cx = cqx + dx;
                if (((unsigned)cz | (unsigned)cy | (unsigned)cx) > 7u) continue;
                const int cell = (cz << 6) | (cy << 3) | cx;
                const int ks = sS[cell], ke = sS[cell + 1];
                for (int k = ks; k < ke; ++k) {
                    const float4 P = sP[k];
                    const int si = sI[k];
                    const float dot = fmaf(qz, P.z, fmaf(qy, P.y, qx * P.x));
                    const float d = fmaf(-2.0f, dot, qq + P.w);
                    ins3(d, si, b0, b1, b2, i0, i1, i2);
                }
            }

    if (half) {
        mD[lq * 3 + 0] = b0; mD[lq * 3 + 1] = b1; mD[lq * 3 + 2] = b2;
        mI[lq * 3 + 0] = i0; mI[lq * 3 + 1] = i1; mI[lq * 3 + 2] = i2;
    }
    __syncthreads();
    if (!half) {
#pragma unroll
        for (int r = 0; r < 3; ++r)
            ins3(mD[lq * 3 + r], mI[lq * 3 + r], b0, b1, b2, i0, i1, i2);

        if (!(b2 < GRID_FAIL_R2)) {            // includes <3-found case (b2=3e38)
            const int p = atomicAdd(failCount, 1);
            if (p < N1R) failList[p] = qid;    // capacity-exact; guard is free
        }
        const float r0 = 1.0f / (fmaxf(b0, 0.0f) + 1e-8f);
        const float r1 = 1.0f / (fmaxf(b1, 0.0f) + 1e-8f);
        const float r2 = 1.0f / (fmaxf(b2, 0.0f) + 1e-8f);
        const float rs = (r0 + r1) + r2;
        idx_out[(size_t)qid * 3 + 0] = i0;
        idx_out[(size_t)qid * 3 + 1] = i1;
        idx_out[(size_t)qid * 3 + 2] = i2;
        w_out[(size_t)qid * 3 + 0] = r0 / rs;
        w_out[(size_t)qid * 3 + 1] = r1 / rs;
        w_out[(size_t)qid * 3 + 2] = r2 / rs;
    }
}

// ---------------------------------------------------------------------------
// Brute-force fallback: one wave per failed query, lanes split 4096 points,
// butterfly shuffle-merge of per-lane top-3 triples.  Exact, tiny workload.
// ---------------------------------------------------------------------------
__global__ __launch_bounds__(256)
void knn_bf_kernel(const float* __restrict__ p1,
                   const float4* __restrict__ paug,
                   const int* __restrict__ failCount,
                   const int* __restrict__ failList,
                   int* __restrict__ idx_out, float* __restrict__ w_out)
{
#pragma clang fp contract(off)
    const int nf = min(*failCount, N1R);
    const int gw = (blockIdx.x * 256 + threadIdx.x) >> 6;
    const int lane = threadIdx.x & 63;
    const int nw = (gridDim.x * 256) >> 6;

    for (int fi = gw; fi < nf; fi += nw) {
        const int qid = failList[fi];
        const int b = qid >> 14;
        const float qx = p1[(size_t)qid * 3 + 0];
        const float qy = p1[(size_t)qid * 3 + 1];
        const float qz = p1[(size_t)qid * 3 + 2];
        const float qq = (qx * qx + qy * qy) + qz * qz;

        float b0 = 3.0e38f, b1 = 3.0e38f, b2 = 3.0e38f;
        int i0 = 0x7fffffff, i1 = 0x7fffffff, i2 = 0x7fffffff;

        const float4* pb = paug + (size_t)b * NPB;
        for (int j = lane; j < NPB; j += 64) {
            const float4 P = pb[j];
            const float dot = fmaf(qz, P.z, fmaf(qy, P.y, qx * P.x));
            const float d = fmaf(-2.0f, dot, qq + P.w);
            ins3(d, j, b0, b1, b2, i0, i1, i2);
        }
        // butterfly merge across the wave
        for (int m = 1; m < 64; m <<= 1) {
            const float c0 = __shfl_xor(b0, m), c1 = __shfl_xor(b1, m), c2 = __shfl_xor(b2, m);
            const int j0 = __shfl_xor(i0, m), j1 = __shfl_xor(i1, m), j2 = __shfl_xor(i2, m);
            ins3(c0, j0, b0, b1, b2, i0, i1, i2);
            ins3(c1, j1, b0, b1, b2, i0, i1, i2);
            ins3(c2, j2, b0, b1, b2, i0, i1, i2);
        }
        if (lane == 0) {
            const float r0 = 1.0f / (fmaxf(b0, 0.0f) + 1e-8f);
            const float r1 = 1.0f / (fmaxf(b1, 0.0f) + 1e-8f);
            const float r2 = 1.0f / (fmaxf(b2, 0.0f) + 1e-8f);
            const float rs = (r0 + r1) + r2;
            idx_out[(size_t)qid * 3 + 0] = i0;
            idx_out[(size_t)qid * 3 + 1] = i1;
            idx_out[(size_t)qid * 3 + 2] = i2;
            w_out[(size_t)qid * 3 + 0] = r0 / rs;
            w_out[(size_t)qid * 3 + 1] = r1 / rs;
            w_out[(size_t)qid * 3 + 2] = r2 / rs;
        }
    }
}

// ---------------------------------------------------------------------------
// Final: out[r][c] = relu(a1*Y1+c1) + sum_k w_k * relu(a2*Y2[idx_k]+c2).
// BN+ReLU of f2 fused into the gather (Y2 stays raw; bnrelu pass removed).
// ---------------------------------------------------------------------------
__global__ __launch_bounds__(256)
void final_kernel(float* __restrict__ Y1out,
                  const float* __restrict__ Y2raw,
                  const float* __restrict__ ac,        // a1,c1,a2,c2 (256 each)
                  const int* __restrict__ idx, const float* __restrict__ w)
{
    const int r = blockIdx.x * 4 + (threadIdx.x >> 6);
    const int cg = threadIdx.x & 63;
    const int b = r >> 14;

    v4f a1 = *(const v4f*)(ac + cg * 4);
    v4f c1 = *(const v4f*)(ac + 256 + cg * 4);
    v4f a2 = *(const v4f*)(ac + 512 + cg * 4);
    v4f c2 = *(const v4f*)(ac + 768 + cg * 4);
    v4f y = *(const v4f*)(Y1out + (size_t)r * CC + cg * 4);
    v4f s;
#pragma unroll
    for (int j = 0; j < 4; ++j)
        s[j] = fmaxf(fmaf(a1[j], y[j], c1[j]), 0.f);

    const int*   ir = idx + (size_t)r * 3;
    const float* wr = w   + (size_t)r * 3;
#pragma unroll
    for (int k = 0; k < 3; ++k) {
        const int id = ir[k];
        const float wk = wr[k];
        v4f g = *(const v4f*)(Y2raw + ((size_t)(b * NPB + id)) * CC + cg * 4);
#pragma unroll
        for (int j = 0; j < 4; ++j) {
            const float gv = fmaxf(fmaf(a2[j], g[j], c2[j]), 0.f);   // == bnrelu
            s[j] = fmaf(wk, gv, s[j]);
        }
    }
    *(v4f*)(Y1out + (size_t)r * CC + cg * 4) = s;
}

// ---------------------------------------------------------------------------
extern "C" void kernel_launch(void* const* d_in, const int* in_sizes, int n_in,
                              void* d_out, int out_size, void* d_ws, size_t ws_size,
                              hipStream_t stream)
{
    const float* point1 = (const float*)d_in[0];
    const float* feat1  = (const float*)d_in[1];
    const float* point2 = (const float*)d_in[2];
    const float* feat2  = (const float*)d_in[3];
    const float* W1     = (const float*)d_in[4];
    const float* b1     = (const float*)d_in[5];
    const float* g1     = (const float*)d_in[6];
    const float* beta1  = (const float*)d_in[7];
    const float* W2     = (const float*)d_in[8];
    const float* b2     = (const float*)d_in[9];
    const float* g2     = (const float*)d_in[10];
    const float* beta2  = (const float*)d_in[11];

    float* Y1 = (float*)d_out;                            // 64 MB (reused as output)

    char* ws = (char*)d_ws;
    float*          Y2       = (float*)ws;                                   // 16 MB (raw, BN fused in final)
    float*          stats    = (float*)(ws + (size_t)16777216);              // 4 KB
    int*            counts_p = (int*)  (ws + (size_t)16781312);              // 8 KB
    int*            counts_q = (int*)  (ws + (size_t)16789504);              // 8 KB
    int*            failCnt  = (int*)  (ws + (size_t)16797696);              // 4 KB pad
    int*            cursors_p= (int*)  (ws + (size_t)16801792);              // 8 KB
    int*            cursors_q= (int*)  (ws + (size_t)16809984);              // 8 KB
    int*            starts_p = (int*)  (ws + (size_t)16818176);              // 8.2 KB
    float*          ac       = (float*)(ws + (size_t)16826624);              // 4 KB
    unsigned short* sIdx16   = (unsigned short*)(ws + (size_t)16830720);     // 32 KB
    unsigned short* qlist    = (unsigned short*)(ws + (size_t)16863488);     // 128 KB
    int*            failList = (int*)  (ws + (size_t)16994560);              // 256 KB
    float4*         sortedP  = (float4*)(ws + (size_t)17256704);             // 256 KB
    int*            idxb     = (int*)  (ws + (size_t)17518848);              // 768 KB
    float*          wb       = (float*)(ws + (size_t)18305280);              // 768 KB
    short*          WT1      = (short*)(ws + (size_t)19091712);              // 128 KB
    short*          WT2      = (short*)(ws + (size_t)19222784);              // 256 KB
    float4*         paug     = (float4*)(ws + (size_t)19484928);             // 256 KB

    // zero: stats (4KB) + counts_p (8KB) + counts_q (8KB) + failCnt (4KB)
    hipMemsetAsync(stats, 0, 24576, stream);

    // Tiny prep kernels
    wtrans_kernel<<<256, 256, 0, stream>>>(W1, WT1, 256);
    wtrans_kernel<<<512, 256, 0, stream>>>(W2, WT2, 512);

    // Cell-grid build: histograms -> prefix/cursors -> scatters
    paug_count_kernel<<<N2R / 256, 256, 0, stream>>>(point2, paug, counts_p);
    qcount_kernel<<<N1R / 256, 256, 0, stream>>>(point1, counts_q);
    prefix_kernel<<<1, 512, 0, stream>>>(counts_p, cursors_p, starts_p, counts_q, cursors_q);
    scatter_p_kernel<<<N2R / 256, 256, 0, stream>>>(paug, cursors_p, sortedP, sIdx16);
    scatter_q_kernel<<<N1R / 256, 256, 0, stream>>>(point1, cursors_q, qlist);

    // Fused GEMM + BN stats: grid = (rows/128, 256/128)
    gemm_fused_kernel<<<dim3(N1R / 128, 2), 256, 0, stream>>>(feat1, WT1, b1, Y1,
                                                              stats + 0,   stats + 256, 256);
    gemm_fused_kernel<<<dim3(N2R / 128, 2), 256, 0, stream>>>(feat2, WT2, b2, Y2,
                                                              stats + 512, stats + 768, 512);

    finalize_kernel<<<1, 512, 0, stream>>>(stats, g1, beta1, g2, beta2, ac);

    // Grid KNN (exact) + brute-force fallback for boundary failures
    knn_grid_kernel<<<512, 256, 0, stream>>>(point1, sortedP, sIdx16, starts_p,
                                             qlist, idxb, wb, failCnt, failList);
    knn_bf_kernel<<<256, 256, 0, stream>>>(point1, paug, failCnt, failList, idxb, wb);

    // out = relu(bn(Y1)) + weighted gather of relu(bn(Y2))  (in-place on d_out)
    final_kernel<<<N1R / 4, 256, 0, stream>>>(Y1, Y2, ac, idxb, wb);
}